// Round 5
// baseline (1069.469 us; speedup 1.0000x reference)
//
#include <hip/hip_runtime.h>
#include <cstdint>

typedef unsigned short u16;
typedef unsigned int   u32;

typedef __bf16 bf16_t;
typedef bf16_t bf16x8 __attribute__((ext_vector_type(8)));
typedef float  f32x16 __attribute__((ext_vector_type(16)));

__device__ __forceinline__ float bf2f(u16 v){ u32 u=((u32)v)<<16; float f; __builtin_memcpy(&f,&u,4); return f; }
__device__ __forceinline__ u16 f2bf(float f){ u32 u; __builtin_memcpy(&u,&f,4); u=(u+0x7FFFu+((u>>16)&1u))>>16; return (u16)u; }

// runtime-dtype element fetch -> bf16 bits. fbf=1: buffer is bf16; fbf=0: fp32.
__device__ __forceinline__ u16 cvt(const void* s, long long i, int fbf){
  return fbf ? ((const u16*)s)[i] : f2bf(((const float*)s)[i]);
}

// ---------------------------------------------------------------------------
// dtype detector (proved correct in round 4: fp32 inputs, int32 idx).
// ---------------------------------------------------------------------------
__global__ void detect_k(const u32* __restrict__ xf, const u32* __restrict__ ix,
                         int* __restrict__ flags){
  __shared__ int c0, c1;
  const int t = threadIdx.x;
  if (t == 0) { c0 = 0; c1 = 0; }
  __syncthreads();
  int a = 0, b = 0;
  for (int i = t; i < 1024; i += 256) {
    u32 w = xf[i];
    int e = (int)((w >> 7) & 0xFFu);
    if (e >= 100 && e <= 140) a++;
  }
  for (int i = t; i < 8192; i += 256) {
    u32 lo = ix[2 * i], hi = ix[2 * i + 1];
    if (lo != 0xFFFFFFFFu && hi != 0u && hi != 0xFFFFFFFFu) b++;
  }
  atomicAdd(&c0, a); atomicAdd(&c1, b);
  __syncthreads();
  if (t == 0) { flags[0] = (c0 >= 768) ? 1 : 0; flags[1] = (c1 == 0) ? 1 : 0; }
}

// ---------------------------------------------------------------------------
// idx transpose: dst[k][p] (int32, k-major, columns padded to Npad with -1,
// rows padded to nKpad with -1). Coalesced global reads via linear copy +
// LDS (257-pad) staging; coalesced writes.
// ---------------------------------------------------------------------------
__global__ void txp_k(const void* __restrict__ idx, int Nd, int nK, int nKpad,
                      int Npad, int* __restrict__ dst, const int* __restrict__ flags){
  __shared__ int tl[28 * 257];
  const int t = threadIdx.x;
  const int P0 = blockIdx.x * 256;
  const int f64 = flags[1];
  const int tot = 256 * nK;
  const long long lim = (long long)Nd * nK;
  for (int i = t; i < tot; i += 256) {
    const long long gi = (long long)P0 * nK + i;
    int v = -1;
    if (gi < lim)
      v = f64 ? (int)((const long long*)idx)[gi] : ((const int*)idx)[gi];
    const int pl = i / nK, k = i - pl * nK;
    tl[k * 257 + pl] = v;
  }
  __syncthreads();
  for (int k = 0; k < nKpad; ++k) {
    int v = (k < nK) ? tl[k * 257 + t] : -1;
    dst[(size_t)k * Npad + P0 + t] = v;
  }
}

// ---------------------------------------------------------------------------
// Gather-GEMM sparse conv, transaction-optimized:
//  - one k-offset per iteration (two for CIN=8), FULL CIN row gathered by
//    LPR consecutive lanes (16B pieces) -> ~4x fewer cache-line transactions
//  - idxT k-major -> coalesced idx reads, no bounds checks in the hot loop
//  - A scatter-written to LDS in MFMA fragment order (minimum-bank pattern),
//    fragment reads lane-linear (conflict-free)
//  - B staged from pre-baked per-iteration images (straight coalesced copy)
// MFMA v_mfma_f32_32x32x16_bf16; M=256/block (8 m-frags, 2/wave).
// C/D: col=lane&31, row=(reg&3)+8*(reg>>2)+4*(lane>>5)
// ---------------------------------------------------------------------------
template<int CIN, int NF>
__global__ __launch_bounds__(256) void gconv(
    const u16* __restrict__ src, int nsrc,          // zero row index = nsrc
    const int* __restrict__ idxT, int Npad, int iters,
    const u16* __restrict__ Bfrag,                  // [it][CPI][NF][64][8] bf16
    const u16* __restrict__ bias,
    const u16* __restrict__ resid,                  // may be null; stride=ostride
    void* __restrict__ out, int ostride, int coloff, int Cout,
    int relu, int Nout,
    const int* __restrict__ flags, int out_ext)
{
  constexpr int CPI = (CIN >= 16) ? CIN / 16 : 1;   // MFMA K-chunks per iter
  __shared__ __align__(16) u16 As[CPI][8][64][8];
  __shared__ __align__(16) u16 Bs[CPI][NF][64][8];
  const int t = threadIdx.x;
  const int w = t >> 6, l = t & 63;
  const int lm = l & 31, lh = l >> 5;
  const int M0 = blockIdx.x * 256;

  f32x16 acc[2][NF];
  #pragma unroll
  for (int mm = 0; mm < 2; ++mm)
    #pragma unroll
    for (int nf = 0; nf < NF; ++nf)
      #pragma unroll
      for (int e = 0; e < 16; ++e) acc[mm][nf][e] = 0.f;

  for (int it = 0; it < iters; ++it) {
    // ---- A staging: full rows, cooperative lanes ----
    if (CIN == 64) {
      const int* idt = idxT + (size_t)it * Npad + M0;
      #pragma unroll
      for (int i = 0; i < 8; ++i) {
        const int r = i * 32 + (t >> 3);
        const int pc = t & 7;
        int j = idt[r];
        const int row = (j < 0 || j > nsrc) ? nsrc : j;
        uint4 v = *(const uint4*)(src + (size_t)row * 64 + pc * 8);
        *(uint4*)&As[pc >> 1][r >> 5][(pc & 1) * 32 + (r & 31)][0] = v;
      }
    } else if (CIN == 32) {
      const int* idt = idxT + (size_t)it * Npad + M0;
      #pragma unroll
      for (int i = 0; i < 4; ++i) {
        const int r = i * 64 + (t >> 2);
        const int pc = t & 3;
        int j = idt[r];
        const int row = (j < 0 || j > nsrc) ? nsrc : j;
        uint4 v = *(const uint4*)(src + (size_t)row * 32 + pc * 8);
        *(uint4*)&As[pc >> 1][r >> 5][(pc & 1) * 32 + (r & 31)][0] = v;
      }
    } else {  // CIN == 8: two k per iteration, 16B row per lane
      #pragma unroll
      for (int i = 0; i < 2; ++i) {
        const int p = i * 128 + (t >> 1);
        const int kk = t & 1;
        int j = idxT[(size_t)(it * 2 + kk) * Npad + M0 + p];
        const int row = (j < 0 || j > nsrc) ? nsrc : j;
        uint4 v = *(const uint4*)(src + (size_t)row * 8);
        *(uint4*)&As[0][p >> 5][kk * 32 + (p & 31)][0] = v;
      }
    }
    // ---- B staging: straight coalesced copy of pre-baked image ----
    {
      const uint4* bsrc = (const uint4*)(Bfrag + (size_t)it * (CPI * NF * 512));
      for (int e = t; e < CPI * NF * 64; e += 256)
        ((uint4*)&Bs[0][0][0][0])[e] = bsrc[e];
    }
    __syncthreads();
    // ---- compute ----
    #pragma unroll
    for (int c = 0; c < CPI; ++c) {
      bf16x8 a0 = *(const bf16x8*)&As[c][2 * w][l][0];
      bf16x8 a1 = *(const bf16x8*)&As[c][2 * w + 1][l][0];
      #pragma unroll
      for (int nf = 0; nf < NF; ++nf) {
        bf16x8 b = *(const bf16x8*)&Bs[c][nf][l][0];
        acc[0][nf] = __builtin_amdgcn_mfma_f32_32x32x16_bf16(a0, b, acc[0][nf], 0, 0, 0);
        acc[1][nf] = __builtin_amdgcn_mfma_f32_32x32x16_bf16(a1, b, acc[1][nf], 0, 0, 0);
      }
    }
    __syncthreads();
  }

  // ---- epilogue: bias (+resid) (+relu), store ----
  const int fp32out = out_ext && !flags[0];
  #pragma unroll
  for (int mm = 0; mm < 2; ++mm) {
    #pragma unroll
    for (int nf = 0; nf < NF; ++nf) {
      const int co = nf * 32 + lm;
      if (co >= Cout) continue;
      const float bv = bf2f(bias[co]);
      #pragma unroll
      for (int r = 0; r < 16; ++r) {
        const int m = (r & 3) + 8 * (r >> 2) + 4 * lh;
        const int p = M0 + (2 * w + mm) * 32 + m;
        if (p >= Nout) continue;
        float v = acc[mm][nf][r] + bv;
        if (resid) v += bf2f(resid[(size_t)p * ostride + coloff + co]);
        if (relu && v < 0.f) v = 0.f;
        const size_t ofs = (size_t)p * ostride + coloff + co;
        if (fp32out) ((float*)out)[ofs] = v;
        else         ((u16*)out)[ofs] = f2bf(v);
      }
    }
  }
}

// ---------------------------------------------------------------------------
// Prep: typ=0 bakes Bfrag[it][c][nf][l][j] = W[k][ci][co] (bf16, zero-padded);
//       typ=1 flat copy-convert (biases, 1x1 weights).
// ---------------------------------------------------------------------------
struct PJob {
  const void* src; long long eoff; u16* dst;
  int typ, nK, CIN, Cout, KPI, NF, CPI, total;
};
struct PArgs { PJob j[22]; };

__global__ void prep_k(PArgs a, const int* __restrict__ flags){
  PJob jb = a.j[blockIdx.y];
  const int fbf = flags[0];
  for (int t0 = blockIdx.x * 256 + threadIdx.x; t0 < jb.total; t0 += gridDim.x * 256) {
    if (jb.typ == 1) { jb.dst[t0] = cvt(jb.src, jb.eoff + t0, fbf); continue; }
    const int j  = t0 & 7;
    const int l  = (t0 >> 3) & 63;
    int rest = t0 >> 9;
    const int nf = rest % jb.NF; rest /= jb.NF;
    const int c  = rest % jb.CPI;
    const int it = rest / jb.CPI;
    const int lh = l >> 5, lm = l & 31;
    const int k  = it * jb.KPI + ((jb.CIN == 8) ? lh : 0);
    const int ci = (jb.CIN == 8) ? j : (c * 16 + lh * 8 + j);
    const int co = nf * 32 + lm;
    u16 v = 0;
    if (k < jb.nK && co < jb.Cout)
      v = cvt(jb.src, jb.eoff + ((long long)(k * jb.CIN + ci) * jb.Cout + co), fbf);
    jb.dst[t0] = v;
  }
}

// xsum = x_feat + f1_ref -> bf16, plus zero row at index N. 8 elems/thread.
__global__ void xsum_k(const void* __restrict__ xa, const void* __restrict__ xb,
                       u16* __restrict__ dst, int n8valid, int n8tot,
                       const int* __restrict__ flags){
  int t = blockIdx.x * 256 + threadIdx.x;
  if (t >= n8tot) return;
  const int fbf = flags[0];
  union { uint4 v; u16 h[8]; } O;
  if (t < n8valid) {
    if (fbf) {
      union { uint4 v; u16 h[8]; } A, B;
      A.v = ((const uint4*)xa)[t];
      B.v = ((const uint4*)xb)[t];
      #pragma unroll
      for (int e = 0; e < 8; ++e) O.h[e] = f2bf(bf2f(A.h[e]) + bf2f(B.h[e]));
    } else {
      const float4* fa = (const float4*)xa;
      const float4* fb = (const float4*)xb;
      float4 a0 = fa[2 * t], a1 = fa[2 * t + 1];
      float4 b0 = fb[2 * t], b1 = fb[2 * t + 1];
      O.h[0] = f2bf(a0.x + b0.x); O.h[1] = f2bf(a0.y + b0.y);
      O.h[2] = f2bf(a0.z + b0.z); O.h[3] = f2bf(a0.w + b0.w);
      O.h[4] = f2bf(a1.x + b1.x); O.h[5] = f2bf(a1.y + b1.y);
      O.h[6] = f2bf(a1.z + b1.z); O.h[7] = f2bf(a1.w + b1.w);
    }
  } else {
    O.v = make_uint4(0, 0, 0, 0);
  }
  ((uint4*)dst)[t] = O.v;
}

// zero the gather "no neighbor" rows (ws re-poisoned every call)
__global__ void zrows_k(u16* out1, int N, u16* od0, u16* od1, u16* h8, u16* t8, int N2){
  int t = threadIdx.x;
  if (t < 64) out1[(size_t)N * 64 + t] = 0;
  if (t < 32) od0[(size_t)N2 * 32 + t] = 0;
  if (t < 32) od1[(size_t)N2 * 32 + t] = 0;
  if (t < 8)  h8[(size_t)N2 * 8 + t] = 0;
  if (t < 8)  t8[(size_t)N2 * 8 + t] = 0;
}

// t8 = relu(od @ W(32x8) + b)   one point/thread. W,b bf16 from ws.
__global__ void t8lin_k(const u16* __restrict__ od, const u16* __restrict__ wsrc,
                        const u16* __restrict__ bsrc, u16* __restrict__ t8, int N2){
  __shared__ u16 wl[256];
  int t = threadIdx.x;
  wl[t] = wsrc[t];
  __syncthreads();
  int p = blockIdx.x * 256 + t;
  if (p >= N2) return;
  union { uint4 v[4]; u16 h[32]; } R;
  const uint4* rp = (const uint4*)(od + (size_t)p * 32);
  R.v[0] = rp[0]; R.v[1] = rp[1]; R.v[2] = rp[2]; R.v[3] = rp[3];
  float acc[8];
  #pragma unroll
  for (int o = 0; o < 8; ++o) acc[o] = bf2f(bsrc[o]);
  #pragma unroll
  for (int c = 0; c < 32; ++c) {
    float f = bf2f(R.h[c]);
    #pragma unroll
    for (int o = 0; o < 8; ++o) acc[o] += f * bf2f(wl[c * 8 + o]);
  }
  union { uint4 v; u16 h[8]; } O;
  #pragma unroll
  for (int o = 0; o < 8; ++o) { float v = acc[o]; if (v < 0.f) v = 0.f; O.h[o] = f2bf(v); }
  ((uint4*)(t8 + (size_t)p * 8))[0] = O.v;
}

// odout[:,16:32] = t2 @ W(8x16) + b + odin[:,16:32]. W,b bf16 from ws.
__global__ void o1lin_k(const u16* __restrict__ t2, const u16* __restrict__ wsrc,
                        const u16* __restrict__ bsrc, const u16* __restrict__ odin,
                        u16* __restrict__ odout, int N2){
  __shared__ u16 wl[128];
  int t = threadIdx.x;
  if (t < 128) wl[t] = wsrc[t];
  __syncthreads();
  int p = blockIdx.x * 256 + t;
  if (p >= N2) return;
  union { uint4 v; u16 h[8]; } R; R.v = ((const uint4*)(t2 + (size_t)p * 8))[0];
  union { uint4 v[2]; u16 h[16]; } Rs;
  const uint4* rp = (const uint4*)(odin + (size_t)p * 32 + 16);
  Rs.v[0] = rp[0]; Rs.v[1] = rp[1];
  float acc[16];
  #pragma unroll
  for (int o = 0; o < 16; ++o) acc[o] = bf2f(bsrc[o]) + bf2f(Rs.h[o]);
  #pragma unroll
  for (int c = 0; c < 8; ++c) {
    float f = bf2f(R.h[c]);
    #pragma unroll
    for (int o = 0; o < 16; ++o) acc[o] += f * bf2f(wl[c * 16 + o]);
  }
  union { uint4 v[2]; u16 h[16]; } O;
  #pragma unroll
  for (int o = 0; o < 16; ++o) O.h[o] = f2bf(acc[o]);
  uint4* op = (uint4*)(odout + (size_t)p * 32 + 16);
  op[0] = O.v[0]; op[1] = O.v[1];
}

extern "C" void kernel_launch(void* const* d_in, const int* in_sizes, int n_in,
                              void* d_out, int out_size, void* d_ws, size_t ws_size,
                              hipStream_t stream) {
  const void* x_feat = d_in[0];
  const void* f1_ref = d_in[1];
  const void* w1   = d_in[2];
  const void* b1   = d_in[3];
  const void* wd   = d_in[4];
  const void* bd   = d_in[5];
  const void* rw00 = d_in[6];
  const void* rb00 = d_in[7];
  const void* rw01 = d_in[8];
  const void* rb01 = d_in[9];
  const void* rw10 = d_in[10];
  const void* rb10 = d_in[11];
  const void* rw11 = d_in[12];
  const void* rb11 = d_in[13];
  const void* rw12 = d_in[14];
  const void* rb12 = d_in[15];
  const void* w4   = d_in[16];
  const void* b4   = d_in[17];
  const void* idx1 = d_in[18];
  const void* idxd = d_in[19];
  const void* idx2 = d_in[20];

  const int N  = in_sizes[0] / 64;
  const int N2 = out_size / 8;
  const int nb1 = (N + 255) / 256,  Npad1 = nb1 * 256;
  const int nb2 = (N2 + 255) / 256, Npad2 = nb2 * 256;

  // ---- workspace carve (256B aligned) ----
  size_t off = 0;
  auto carve = [&](size_t n) { void* p = (char*)d_ws + off; off = (off + n + 255) & ~(size_t)255; return p; };
  int* flags = (int*)carve(64 * sizeof(int));
  u16* xsum = (u16*)carve((size_t)(N + 1) * 64 * 2);
  u16* out1 = (u16*)carve((size_t)(N + 1) * 64 * 2);
  size_t od_begin = off;
  u16* od0  = (u16*)carve((size_t)(N2 + 1) * 32 * 2);
  u16* od1  = (u16*)carve((size_t)(N2 + 1) * 32 * 2);
  u16* h8   = (u16*)carve((size_t)(N2 + 1) * 8 * 2);
  u16* t8   = (u16*)carve((size_t)(N2 + 1) * 8 * 2);
  u16* t2   = (u16*)carve((size_t)(N2 + 1) * 8 * 2);
  size_t od_end = off;
  u16* smallw = (u16*)carve((size_t)2048 * 2);
  u16* fb1  = (u16*)carve((size_t)110592 * 2);
  u16* fbd  = (u16*)carve((size_t)16384 * 2);
  u16* fb00 = (u16*)carve((size_t)3 * 27648 * 2);
  u16* fb01 = (u16*)carve((size_t)3 * 7168 * 2);
  u16* fb11 = (u16*)carve((size_t)3 * 7168 * 2);
  u16* fb4  = (u16*)carve((size_t)27648 * 2);
  if (off > ws_size) return;

  // idxT1: prefer its own carve; else alias the od-region (dead until after
  // conv1 — txp1 runs first, zrows/down deferred until conv1 is done).
  const size_t idxT1_bytes = (size_t)27 * Npad1 * 4;
  int* idxT1;
  if (off + idxT1_bytes + 256 <= ws_size) {
    idxT1 = (int*)carve(idxT1_bytes);
  } else if (od_end - od_begin >= idxT1_bytes) {
    idxT1 = (int*)od0;
  } else {
    return;
  }
  // idxTd aliases xsum (txp_d after conv1); idxT2 aliases out1 (txp_2 after down).
  int* idxTd = (int*)xsum;
  int* idxT2 = (int*)out1;

  // smallw layout (bf16 elements)
  u16* cb1   = smallw + 0;     // 64
  u16* cbd   = smallw + 64;    // 32
  u16* crb00 = smallw + 96;    // 24
  u16* crb01 = smallw + 120;   // 48
  u16* crb10 = smallw + 168;   // 24
  u16* crb11 = smallw + 192;   // 24
  u16* crb12 = smallw + 216;   // 48
  u16* cb4   = smallw + 264;   // 8
  u16* crw10 = smallw + 272;   // 768
  u16* crw12 = smallw + 1040;  // 384

  detect_k<<<1, 256, 0, stream>>>((const u32*)x_feat, (const u32*)idx1, flags);
  txp_k<<<nb1, 256, 0, stream>>>(idx1, N, 27, 27, Npad1, idxT1, flags);

  // ---- weight prep ----
  PArgs pa;
  pa.j[0] = { w1, 0, fb1, 0, 27, 64, 64, 1, 2, 4, 110592 };
  pa.j[1] = { wd, 0, fbd, 0,  8, 64, 32, 1, 1, 4,  16384 };
  for (int i = 0; i < 3; ++i) {
    pa.j[2 + i] = { rw00, (long long)i * 6912, fb00 + (size_t)i * 27648, 0, 27, 32,  8, 1, 1, 2, 27648 };
    pa.j[5 + i] = { rw01, (long long)i * 3456, fb01 + (size_t)i * 7168,  0, 27,  8, 16, 2, 1, 1,  7168 };
    pa.j[8 + i] = { rw11, (long long)i * 1728, fb11 + (size_t)i * 7168,  0, 27,  8,  8, 2, 1, 1,  7168 };
  }
  pa.j[11] = { w4, 0, fb4, 0, 27, 32, 8, 1, 1, 2, 27648 };
  pa.j[12] = { b1,   0, cb1,   1, 0,0,0,0,1,1, 64 };
  pa.j[13] = { bd,   0, cbd,   1, 0,0,0,0,1,1, 32 };
  pa.j[14] = { rb00, 0, crb00, 1, 0,0,0,0,1,1, 24 };
  pa.j[15] = { rb01, 0, crb01, 1, 0,0,0,0,1,1, 48 };
  pa.j[16] = { rb10, 0, crb10, 1, 0,0,0,0,1,1, 24 };
  pa.j[17] = { rb11, 0, crb11, 1, 0,0,0,0,1,1, 24 };
  pa.j[18] = { rb12, 0, crb12, 1, 0,0,0,0,1,1, 48 };
  pa.j[19] = { b4,   0, cb4,   1, 0,0,0,0,1,1, 8 };
  pa.j[20] = { rw10, 0, crw10, 1, 0,0,0,0,1,1, 768 };
  pa.j[21] = { rw12, 0, crw12, 1, 0,0,0,0,1,1, 384 };
  prep_k<<<dim3(432, 22), 256, 0, stream>>>(pa, flags);

  const int n8valid = N * 8, n8tot = (N + 1) * 8;
  xsum_k<<<(n8tot + 255) / 256, 256, 0, stream>>>(x_feat, f1_ref, xsum, n8valid, n8tot, flags);

  // conv1: 27x64->64, relu
  gconv<64, 2><<<nb1, 256, 0, stream>>>(xsum, N, idxT1, Npad1, 27, fb1,
                                        cb1, nullptr, out1, 64, 0, 64, 1, N, flags, 0);
  // idxT1 + xsum now dead; stage remaining transposes into aliased regions
  txp_k<<<nb2, 256, 0, stream>>>(idxd, N2, 8, 8, Npad2, idxTd, flags);
  zrows_k<<<1, 256, 0, stream>>>(out1, N, od0, od1, h8, t8, N2);

  // down: 8x64->32, relu
  gconv<64, 1><<<nb2, 256, 0, stream>>>(out1, N, idxTd, Npad2, 8, fbd,
                                        cbd, nullptr, od0, 32, 0, 32, 1, N2, flags, 0);
  // out1 now dead
  txp_k<<<nb2, 256, 0, stream>>>(idx2, N2, 27, 28, Npad2, idxT2, flags);

  // residual blocks
  for (int i = 0; i < 3; ++i) {
    u16* oin  = (i & 1) ? od1 : od0;
    u16* oout = (i & 1) ? od0 : od1;
    gconv<32, 1><<<nb2, 256, 0, stream>>>(oin, N2, idxT2, Npad2, 27, fb00 + (size_t)i * 27648,
                                          crb00 + i * 8, nullptr, h8, 8, 0, 8, 1, N2, flags, 0);
    t8lin_k<<<nb2, 256, 0, stream>>>(oin, crw10 + i * 256, crb10 + i * 8, t8, N2);
    gconv<8, 1><<<nb2, 256, 0, stream>>>(h8, N2, idxT2, Npad2, 14, fb01 + (size_t)i * 7168,
                                         crb01 + i * 16, oin, oout, 32, 0, 16, 0, N2, flags, 0);
    gconv<8, 1><<<nb2, 256, 0, stream>>>(t8, N2, idxT2, Npad2, 14, fb11 + (size_t)i * 7168,
                                         crb11 + i * 8, nullptr, t2, 8, 0, 8, 1, N2, flags, 0);
    o1lin_k<<<nb2, 256, 0, stream>>>(t2, crw12 + i * 128, crb12 + i * 16, oin, oout, N2);
  }
  // enc4: 27x32->8, no relu -> d_out (dtype per flags[0])
  gconv<32, 1><<<nb2, 256, 0, stream>>>(od1, N2, idxT2, Npad2, 27, fb4,
                                        cb4, nullptr, d_out, 8, 0, 8, 0, N2, flags, 1);
}

// Round 6
// 1032.702 us; speedup vs baseline: 1.0356x; 1.0356x over previous
//
#include <hip/hip_runtime.h>
#include <cstdint>

typedef unsigned short u16;
typedef unsigned int   u32;

typedef __bf16 bf16_t;
typedef bf16_t bf16x8 __attribute__((ext_vector_type(8)));
typedef float  f32x16 __attribute__((ext_vector_type(16)));

__device__ __forceinline__ float bf2f(u16 v){ u32 u=((u32)v)<<16; float f; __builtin_memcpy(&f,&u,4); return f; }
__device__ __forceinline__ u16 f2bf(float f){ u32 u; __builtin_memcpy(&u,&f,4); u=(u+0x7FFFu+((u>>16)&1u))>>16; return (u16)u; }

// runtime-dtype element fetch -> bf16 bits. fbf=1: buffer is bf16; fbf=0: fp32.
__device__ __forceinline__ u16 cvt(const void* s, long long i, int fbf){
  return fbf ? ((const u16*)s)[i] : f2bf(((const float*)s)[i]);
}

// ---------------------------------------------------------------------------
// dtype detector (proved correct in round 4: fp32 inputs, int32 idx).
// ---------------------------------------------------------------------------
__global__ void detect_k(const u32* __restrict__ xf, const u32* __restrict__ ix,
                         int* __restrict__ flags){
  __shared__ int c0, c1;
  const int t = threadIdx.x;
  if (t == 0) { c0 = 0; c1 = 0; }
  __syncthreads();
  int a = 0, b = 0;
  for (int i = t; i < 1024; i += 256) {
    u32 w = xf[i];
    int e = (int)((w >> 7) & 0xFFu);
    if (e >= 100 && e <= 140) a++;
  }
  for (int i = t; i < 8192; i += 256) {
    u32 lo = ix[2 * i], hi = ix[2 * i + 1];
    if (lo != 0xFFFFFFFFu && hi != 0u && hi != 0xFFFFFFFFu) b++;
  }
  atomicAdd(&c0, a); atomicAdd(&c1, b);
  __syncthreads();
  if (t == 0) { flags[0] = (c0 >= 768) ? 1 : 0; flags[1] = (c1 == 0) ? 1 : 0; }
}

// ---------------------------------------------------------------------------
// idx transpose: dst[k][p] (int32, k-major, padded with -1).
// ---------------------------------------------------------------------------
__global__ void txp_k(const void* __restrict__ idx, int Nd, int nK, int nKpad,
                      int Npad, int* __restrict__ dst, const int* __restrict__ flags){
  __shared__ int tl[28 * 257];
  const int t = threadIdx.x;
  const int P0 = blockIdx.x * 256;
  const int f64 = flags[1];
  const int tot = 256 * nK;
  const long long lim = (long long)Nd * nK;
  for (int i = t; i < tot; i += 256) {
    const long long gi = (long long)P0 * nK + i;
    int v = -1;
    if (gi < lim)
      v = f64 ? (int)((const long long*)idx)[gi] : ((const int*)idx)[gi];
    const int pl = i / nK, k = i - pl * nK;
    tl[k * 257 + pl] = v;
  }
  __syncthreads();
  for (int k = 0; k < nKpad; ++k) {
    int v = (k < nK) ? tl[k * 257 + t] : -1;
    dst[(size_t)k * Npad + P0 + t] = v;
  }
}

// ---------------------------------------------------------------------------
// Gather-GEMM sparse conv, transaction-optimized + LDS-swizzled:
//  - full CIN row gathered by consecutive lanes (16B pieces) -> few line txns
//  - idxT k-major -> coalesced idx reads
//  - A stored with XOR swizzle: logical slot sl of chunk c lives at
//    sl ^ pc, pc = 2c + (sl>>5). Round-5 lesson (SQ_LDS_BANK_CONFLICT=4.7e7):
//    LDS services b128 in consecutive-8-lane phases; each phase needs 8
//    DISTINCT 16B-slot residues mod 8. Swizzle gives distinct residues on
//    both write (r ^ pc) and read (l ^ const) sides. CIN=8 is 2-way (free).
//  - B staged from pre-baked per-iteration images (straight coalesced copy)
// MFMA v_mfma_f32_32x32x16_bf16; M=256/block (8 m-frags, 2/wave).
// C/D: col=lane&31, row=(reg&3)+8*(reg>>2)+4*(lane>>5)
// ---------------------------------------------------------------------------
template<int CIN, int NF>
__global__ __launch_bounds__(256) void gconv(
    const u16* __restrict__ src, int nsrc,          // zero row index = nsrc
    const int* __restrict__ idxT, int Npad, int iters,
    const u16* __restrict__ Bfrag,                  // [it][CPI][NF][64][8] bf16
    const u16* __restrict__ bias,
    const u16* __restrict__ resid,                  // may be null; stride=ostride
    void* __restrict__ out, int ostride, int coloff, int Cout,
    int relu, int Nout,
    const int* __restrict__ flags, int out_ext)
{
  constexpr int CPI = (CIN >= 16) ? CIN / 16 : 1;   // MFMA K-chunks per iter
  __shared__ __align__(16) u16 As[CPI][8][64][8];
  __shared__ __align__(16) u16 Bs[CPI][NF][64][8];
  const int t = threadIdx.x;
  const int w = t >> 6, l = t & 63;
  const int lm = l & 31, lh = l >> 5;
  const int M0 = blockIdx.x * 256;

  f32x16 acc[2][NF];
  #pragma unroll
  for (int mm = 0; mm < 2; ++mm)
    #pragma unroll
    for (int nf = 0; nf < NF; ++nf)
      #pragma unroll
      for (int e = 0; e < 16; ++e) acc[mm][nf][e] = 0.f;

  for (int it = 0; it < iters; ++it) {
    // ---- A staging: full rows, cooperative lanes, swizzled LDS write ----
    if (CIN == 64) {
      const int* idt = idxT + (size_t)it * Npad + M0;
      #pragma unroll
      for (int i = 0; i < 8; ++i) {
        const int r = i * 32 + (t >> 3);
        const int pc = t & 7;
        int j = idt[r];
        const int row = (j < 0 || j > nsrc) ? nsrc : j;
        uint4 v = *(const uint4*)(src + (size_t)row * 64 + pc * 8);
        const int slw = (((pc & 1) << 5) | (r & 31)) ^ pc;
        *(uint4*)&As[pc >> 1][r >> 5][slw][0] = v;
      }
    } else if (CIN == 32) {
      const int* idt = idxT + (size_t)it * Npad + M0;
      #pragma unroll
      for (int i = 0; i < 4; ++i) {
        const int r = i * 64 + (t >> 2);
        const int pc = t & 3;
        int j = idt[r];
        const int row = (j < 0 || j > nsrc) ? nsrc : j;
        uint4 v = *(const uint4*)(src + (size_t)row * 32 + pc * 8);
        const int slw = (((pc & 1) << 5) | (r & 31)) ^ pc;
        *(uint4*)&As[pc >> 1][r >> 5][slw][0] = v;
      }
    } else {  // CIN == 8: two k per iteration, 16B row per lane (2-way: free)
      #pragma unroll
      for (int i = 0; i < 2; ++i) {
        const int p = i * 128 + (t >> 1);
        const int kk = t & 1;
        int j = idxT[(size_t)(it * 2 + kk) * Npad + M0 + p];
        const int row = (j < 0 || j > nsrc) ? nsrc : j;
        uint4 v = *(const uint4*)(src + (size_t)row * 8);
        *(uint4*)&As[0][p >> 5][kk * 32 + (p & 31)][0] = v;
      }
    }
    // ---- B staging: straight coalesced copy of pre-baked image ----
    {
      const uint4* bsrc = (const uint4*)(Bfrag + (size_t)it * (CPI * NF * 512));
      for (int e = t; e < CPI * NF * 64; e += 256)
        ((uint4*)&Bs[0][0][0][0])[e] = bsrc[e];
    }
    __syncthreads();
    // ---- compute (swizzled A read for CIN>=32) ----
    #pragma unroll
    for (int c = 0; c < CPI; ++c) {
      const int slr = (CIN >= 32) ? (l ^ (2 * c + lh)) : l;
      bf16x8 a0 = *(const bf16x8*)&As[c][2 * w][slr][0];
      bf16x8 a1 = *(const bf16x8*)&As[c][2 * w + 1][slr][0];
      #pragma unroll
      for (int nf = 0; nf < NF; ++nf) {
        bf16x8 b = *(const bf16x8*)&Bs[c][nf][l][0];
        acc[0][nf] = __builtin_amdgcn_mfma_f32_32x32x16_bf16(a0, b, acc[0][nf], 0, 0, 0);
        acc[1][nf] = __builtin_amdgcn_mfma_f32_32x32x16_bf16(a1, b, acc[1][nf], 0, 0, 0);
      }
    }
    __syncthreads();
  }

  // ---- epilogue: bias (+resid) (+relu), store ----
  const int fp32out = out_ext && !flags[0];
  #pragma unroll
  for (int mm = 0; mm < 2; ++mm) {
    #pragma unroll
    for (int nf = 0; nf < NF; ++nf) {
      const int co = nf * 32 + lm;
      if (co >= Cout) continue;
      const float bv = bf2f(bias[co]);
      #pragma unroll
      for (int r = 0; r < 16; ++r) {
        const int m = (r & 3) + 8 * (r >> 2) + 4 * lh;
        const int p = M0 + (2 * w + mm) * 32 + m;
        if (p >= Nout) continue;
        float v = acc[mm][nf][r] + bv;
        if (resid) v += bf2f(resid[(size_t)p * ostride + coloff + co]);
        if (relu && v < 0.f) v = 0.f;
        const size_t ofs = (size_t)p * ostride + coloff + co;
        if (fp32out) ((float*)out)[ofs] = v;
        else         ((u16*)out)[ofs] = f2bf(v);
      }
    }
  }
}

// ---------------------------------------------------------------------------
// Prep: typ=0 bakes Bfrag[it][c][nf][l][j] = W[k][ci][co] (bf16, zero-padded);
//       typ=1 flat copy-convert (biases, 1x1 weights).
// ---------------------------------------------------------------------------
struct PJob {
  const void* src; long long eoff; u16* dst;
  int typ, nK, CIN, Cout, KPI, NF, CPI, total;
};
struct PArgs { PJob j[22]; };

__global__ void prep_k(PArgs a, const int* __restrict__ flags){
  PJob jb = a.j[blockIdx.y];
  const int fbf = flags[0];
  for (int t0 = blockIdx.x * 256 + threadIdx.x; t0 < jb.total; t0 += gridDim.x * 256) {
    if (jb.typ == 1) { jb.dst[t0] = cvt(jb.src, jb.eoff + t0, fbf); continue; }
    const int j  = t0 & 7;
    const int l  = (t0 >> 3) & 63;
    int rest = t0 >> 9;
    const int nf = rest % jb.NF; rest /= jb.NF;
    const int c  = rest % jb.CPI;
    const int it = rest / jb.CPI;
    const int lh = l >> 5, lm = l & 31;
    const int k  = it * jb.KPI + ((jb.CIN == 8) ? lh : 0);
    const int ci = (jb.CIN == 8) ? j : (c * 16 + lh * 8 + j);
    const int co = nf * 32 + lm;
    u16 v = 0;
    if (k < jb.nK && co < jb.Cout)
      v = cvt(jb.src, jb.eoff + ((long long)(k * jb.CIN + ci) * jb.Cout + co), fbf);
    jb.dst[t0] = v;
  }
}

// xsum = x_feat + f1_ref -> bf16, plus zero row at index N. 8 elems/thread.
__global__ void xsum_k(const void* __restrict__ xa, const void* __restrict__ xb,
                       u16* __restrict__ dst, int n8valid, int n8tot,
                       const int* __restrict__ flags){
  int t = blockIdx.x * 256 + threadIdx.x;
  if (t >= n8tot) return;
  const int fbf = flags[0];
  union { uint4 v; u16 h[8]; } O;
  if (t < n8valid) {
    if (fbf) {
      union { uint4 v; u16 h[8]; } A, B;
      A.v = ((const uint4*)xa)[t];
      B.v = ((const uint4*)xb)[t];
      #pragma unroll
      for (int e = 0; e < 8; ++e) O.h[e] = f2bf(bf2f(A.h[e]) + bf2f(B.h[e]));
    } else {
      const float4* fa = (const float4*)xa;
      const float4* fb = (const float4*)xb;
      float4 a0 = fa[2 * t], a1 = fa[2 * t + 1];
      float4 b0 = fb[2 * t], b1 = fb[2 * t + 1];
      O.h[0] = f2bf(a0.x + b0.x); O.h[1] = f2bf(a0.y + b0.y);
      O.h[2] = f2bf(a0.z + b0.z); O.h[3] = f2bf(a0.w + b0.w);
      O.h[4] = f2bf(a1.x + b1.x); O.h[5] = f2bf(a1.y + b1.y);
      O.h[6] = f2bf(a1.z + b1.z); O.h[7] = f2bf(a1.w + b1.w);
    }
  } else {
    O.v = make_uint4(0, 0, 0, 0);
  }
  ((uint4*)dst)[t] = O.v;
}

// zero the gather "no neighbor" rows (ws re-poisoned every call)
__global__ void zrows_k(u16* out1, int N, u16* od0, u16* od1, u16* h8, u16* t8, int N2){
  int t = threadIdx.x;
  if (t < 64) out1[(size_t)N * 64 + t] = 0;
  if (t < 32) od0[(size_t)N2 * 32 + t] = 0;
  if (t < 32) od1[(size_t)N2 * 32 + t] = 0;
  if (t < 8)  h8[(size_t)N2 * 8 + t] = 0;
  if (t < 8)  t8[(size_t)N2 * 8 + t] = 0;
}

// t8 = relu(od @ W(32x8) + b)   one point/thread. W,b bf16 from ws.
__global__ void t8lin_k(const u16* __restrict__ od, const u16* __restrict__ wsrc,
                        const u16* __restrict__ bsrc, u16* __restrict__ t8, int N2){
  __shared__ u16 wl[256];
  int t = threadIdx.x;
  wl[t] = wsrc[t];
  __syncthreads();
  int p = blockIdx.x * 256 + t;
  if (p >= N2) return;
  union { uint4 v[4]; u16 h[32]; } R;
  const uint4* rp = (const uint4*)(od + (size_t)p * 32);
  R.v[0] = rp[0]; R.v[1] = rp[1]; R.v[2] = rp[2]; R.v[3] = rp[3];
  float acc[8];
  #pragma unroll
  for (int o = 0; o < 8; ++o) acc[o] = bf2f(bsrc[o]);
  #pragma unroll
  for (int c = 0; c < 32; ++c) {
    float f = bf2f(R.h[c]);
    #pragma unroll
    for (int o = 0; o < 8; ++o) acc[o] += f * bf2f(wl[c * 8 + o]);
  }
  union { uint4 v; u16 h[8]; } O;
  #pragma unroll
  for (int o = 0; o < 8; ++o) { float v = acc[o]; if (v < 0.f) v = 0.f; O.h[o] = f2bf(v); }
  ((uint4*)(t8 + (size_t)p * 8))[0] = O.v;
}

// odout[:,16:32] = t2 @ W(8x16) + b + odin[:,16:32]. W,b bf16 from ws.
__global__ void o1lin_k(const u16* __restrict__ t2, const u16* __restrict__ wsrc,
                        const u16* __restrict__ bsrc, const u16* __restrict__ odin,
                        u16* __restrict__ odout, int N2){
  __shared__ u16 wl[128];
  int t = threadIdx.x;
  if (t < 128) wl[t] = wsrc[t];
  __syncthreads();
  int p = blockIdx.x * 256 + t;
  if (p >= N2) return;
  union { uint4 v; u16 h[8]; } R; R.v = ((const uint4*)(t2 + (size_t)p * 8))[0];
  union { uint4 v[2]; u16 h[16]; } Rs;
  const uint4* rp = (const uint4*)(odin + (size_t)p * 32 + 16);
  Rs.v[0] = rp[0]; Rs.v[1] = rp[1];
  float acc[16];
  #pragma unroll
  for (int o = 0; o < 16; ++o) acc[o] = bf2f(bsrc[o]) + bf2f(Rs.h[o]);
  #pragma unroll
  for (int c = 0; c < 8; ++c) {
    float f = bf2f(R.h[c]);
    #pragma unroll
    for (int o = 0; o < 16; ++o) acc[o] += f * bf2f(wl[c * 16 + o]);
  }
  union { uint4 v[2]; u16 h[16]; } O;
  #pragma unroll
  for (int o = 0; o < 16; ++o) O.h[o] = f2bf(acc[o]);
  uint4* op = (uint4*)(odout + (size_t)p * 32 + 16);
  op[0] = O.v[0]; op[1] = O.v[1];
}

extern "C" void kernel_launch(void* const* d_in, const int* in_sizes, int n_in,
                              void* d_out, int out_size, void* d_ws, size_t ws_size,
                              hipStream_t stream) {
  const void* x_feat = d_in[0];
  const void* f1_ref = d_in[1];
  const void* w1   = d_in[2];
  const void* b1   = d_in[3];
  const void* wd   = d_in[4];
  const void* bd   = d_in[5];
  const void* rw00 = d_in[6];
  const void* rb00 = d_in[7];
  const void* rw01 = d_in[8];
  const void* rb01 = d_in[9];
  const void* rw10 = d_in[10];
  const void* rb10 = d_in[11];
  const void* rw11 = d_in[12];
  const void* rb11 = d_in[13];
  const void* rw12 = d_in[14];
  const void* rb12 = d_in[15];
  const void* w4   = d_in[16];
  const void* b4   = d_in[17];
  const void* idx1 = d_in[18];
  const void* idxd = d_in[19];
  const void* idx2 = d_in[20];

  const int N  = in_sizes[0] / 64;
  const int N2 = out_size / 8;
  const int nb1 = (N + 255) / 256,  Npad1 = nb1 * 256;
  const int nb2 = (N2 + 255) / 256, Npad2 = nb2 * 256;

  // ---- workspace carve (256B aligned) ----
  size_t off = 0;
  auto carve = [&](size_t n) { void* p = (char*)d_ws + off; off = (off + n + 255) & ~(size_t)255; return p; };
  int* flags = (int*)carve(64 * sizeof(int));
  u16* xsum = (u16*)carve((size_t)(N + 1) * 64 * 2);
  u16* out1 = (u16*)carve((size_t)(N + 1) * 64 * 2);
  size_t od_begin = off;
  u16* od0  = (u16*)carve((size_t)(N2 + 1) * 32 * 2);
  u16* od1  = (u16*)carve((size_t)(N2 + 1) * 32 * 2);
  u16* h8   = (u16*)carve((size_t)(N2 + 1) * 8 * 2);
  u16* t8   = (u16*)carve((size_t)(N2 + 1) * 8 * 2);
  u16* t2   = (u16*)carve((size_t)(N2 + 1) * 8 * 2);
  size_t od_end = off;
  u16* smallw = (u16*)carve((size_t)2048 * 2);
  u16* fb1  = (u16*)carve((size_t)110592 * 2);
  u16* fbd  = (u16*)carve((size_t)16384 * 2);
  u16* fb00 = (u16*)carve((size_t)3 * 27648 * 2);
  u16* fb01 = (u16*)carve((size_t)3 * 7168 * 2);
  u16* fb11 = (u16*)carve((size_t)3 * 7168 * 2);
  u16* fb4  = (u16*)carve((size_t)27648 * 2);
  if (off > ws_size) return;

  // idxT1: prefer its own carve; else alias the od-region (dead until after
  // conv1 — txp1 runs first, zrows/down deferred until conv1 is done).
  const size_t idxT1_bytes = (size_t)27 * Npad1 * 4;
  int* idxT1;
  if (off + idxT1_bytes + 256 <= ws_size) {
    idxT1 = (int*)carve(idxT1_bytes);
  } else if (od_end - od_begin >= idxT1_bytes) {
    idxT1 = (int*)od0;
  } else {
    return;
  }
  // idxTd aliases xsum (txp_d after conv1); idxT2 aliases out1 (txp_2 after down).
  int* idxTd = (int*)xsum;
  int* idxT2 = (int*)out1;

  // smallw layout (bf16 elements)
  u16* cb1   = smallw + 0;     // 64
  u16* cbd   = smallw + 64;    // 32
  u16* crb00 = smallw + 96;    // 24
  u16* crb01 = smallw + 120;   // 48
  u16* crb10 = smallw + 168;   // 24
  u16* crb11 = smallw + 192;   // 24
  u16* crb12 = smallw + 216;   // 48
  u16* cb4   = smallw + 264;   // 8
  u16* crw10 = smallw + 272;   // 768
  u16* crw12 = smallw + 1040;  // 384

  detect_k<<<1, 256, 0, stream>>>((const u32*)x_feat, (const u32*)idx1, flags);
  txp_k<<<nb1, 256, 0, stream>>>(idx1, N, 27, 27, Npad1, idxT1, flags);

  // ---- weight prep ----
  PArgs pa;
  pa.j[0] = { w1, 0, fb1, 0, 27, 64, 64, 1, 2, 4, 110592 };
  pa.j[1] = { wd, 0, fbd, 0,  8, 64, 32, 1, 1, 4,  16384 };
  for (int i = 0; i < 3; ++i) {
    pa.j[2 + i] = { rw00, (long long)i * 6912, fb00 + (size_t)i * 27648, 0, 27, 32,  8, 1, 1, 2, 27648 };
    pa.j[5 + i] = { rw01, (long long)i * 3456, fb01 + (size_t)i * 7168,  0, 27,  8, 16, 2, 1, 1,  7168 };
    pa.j[8 + i] = { rw11, (long long)i * 1728, fb11 + (size_t)i * 7168,  0, 27,  8,  8, 2, 1, 1,  7168 };
  }
  pa.j[11] = { w4, 0, fb4, 0, 27, 32, 8, 1, 1, 2, 27648 };
  pa.j[12] = { b1,   0, cb1,   1, 0,0,0,0,1,1, 64 };
  pa.j[13] = { bd,   0, cbd,   1, 0,0,0,0,1,1, 32 };
  pa.j[14] = { rb00, 0, crb00, 1, 0,0,0,0,1,1, 24 };
  pa.j[15] = { rb01, 0, crb01, 1, 0,0,0,0,1,1, 48 };
  pa.j[16] = { rb10, 0, crb10, 1, 0,0,0,0,1,1, 24 };
  pa.j[17] = { rb11, 0, crb11, 1, 0,0,0,0,1,1, 24 };
  pa.j[18] = { rb12, 0, crb12, 1, 0,0,0,0,1,1, 48 };
  pa.j[19] = { b4,   0, cb4,   1, 0,0,0,0,1,1, 8 };
  pa.j[20] = { rw10, 0, crw10, 1, 0,0,0,0,1,1, 768 };
  pa.j[21] = { rw12, 0, crw12, 1, 0,0,0,0,1,1, 384 };
  prep_k<<<dim3(432, 22), 256, 0, stream>>>(pa, flags);

  const int n8valid = N * 8, n8tot = (N + 1) * 8;
  xsum_k<<<(n8tot + 255) / 256, 256, 0, stream>>>(x_feat, f1_ref, xsum, n8valid, n8tot, flags);

  // conv1: 27x64->64, relu
  gconv<64, 2><<<nb1, 256, 0, stream>>>(xsum, N, idxT1, Npad1, 27, fb1,
                                        cb1, nullptr, out1, 64, 0, 64, 1, N, flags, 0);
  // idxT1 + xsum now dead; stage remaining transposes into aliased regions
  txp_k<<<nb2, 256, 0, stream>>>(idxd, N2, 8, 8, Npad2, idxTd, flags);
  zrows_k<<<1, 256, 0, stream>>>(out1, N, od0, od1, h8, t8, N2);

  // down: 8x64->32, relu
  gconv<64, 1><<<nb2, 256, 0, stream>>>(out1, N, idxTd, Npad2, 8, fbd,
                                        cbd, nullptr, od0, 32, 0, 32, 1, N2, flags, 0);
  // out1 now dead
  txp_k<<<nb2, 256, 0, stream>>>(idx2, N2, 27, 28, Npad2, idxT2, flags);

  // residual blocks
  for (int i = 0; i < 3; ++i) {
    u16* oin  = (i & 1) ? od1 : od0;
    u16* oout = (i & 1) ? od0 : od1;
    gconv<32, 1><<<nb2, 256, 0, stream>>>(oin, N2, idxT2, Npad2, 27, fb00 + (size_t)i * 27648,
                                          crb00 + i * 8, nullptr, h8, 8, 0, 8, 1, N2, flags, 0);
    t8lin_k<<<nb2, 256, 0, stream>>>(oin, crw10 + i * 256, crb10 + i * 8, t8, N2);
    gconv<8, 1><<<nb2, 256, 0, stream>>>(h8, N2, idxT2, Npad2, 14, fb01 + (size_t)i * 7168,
                                         crb01 + i * 16, oin, oout, 32, 0, 16, 0, N2, flags, 0);
    gconv<8, 1><<<nb2, 256, 0, stream>>>(t8, N2, idxT2, Npad2, 14, fb11 + (size_t)i * 7168,
                                         crb11 + i * 8, nullptr, t2, 8, 0, 8, 1, N2, flags, 0);
    o1lin_k<<<nb2, 256, 0, stream>>>(t2, crw12 + i * 128, crb12 + i * 16, oin, oout, N2);
  }
  // enc4: 27x32->8, no relu -> d_out (dtype per flags[0])
  gconv<32, 1><<<nb2, 256, 0, stream>>>(od1, N2, idxT2, Npad2, 27, fb4,
                                        cb4, nullptr, d_out, 8, 0, 8, 0, N2, flags, 1);
}